// Round 1
// baseline (93830.188 us; speedup 1.0000x reference)
//
#include <hip/hip_runtime.h>
#include <stdint.h>
#include <stddef.h>

#define T_SEQ 8192
#define HDIM  2048
#define NB    256
#define NT    256

// workspace layout (bytes):
//   [0,512)        : 8 counters, one per 64B line (int at k*16)
//   [512,16896)    : hbuf float[2][2048]
//   [16896,49664)  : feat float[8192]
//   [49664,57856)  : hid  float[2048]
#define WS_ZERO_DWORDS 16384   // zero first 64KB

__global__ void init_ws_kernel(uint32_t* ws) {
    int i = blockIdx.x * blockDim.x + threadIdx.x;
    if (i < WS_ZERO_DWORDS) ws[i] = 0u;
}

__device__ __forceinline__ float sigm(float xv) { return 1.0f / (1.0f + expf(-xv)); }

__global__ __launch_bounds__(NT, 1) void policy_persistent(
    const float* __restrict__ x,      // (8192,3)
    const float* __restrict__ ldist,  // scalar
    const float* __restrict__ lhead,  // scalar
    const float* __restrict__ W_ih,   // (8192,3)
    const float* __restrict__ W_hh,   // (8192,2048)
    const float* __restrict__ b_ih,   // (8192)
    const float* __restrict__ b_hh,   // (8192)
    const float* __restrict__ W1,     // (2048,8192)
    const float* __restrict__ b1,     // (2048)
    const float* __restrict__ W2,     // (4,2048)
    const float* __restrict__ b2,     // (4)
    float* __restrict__ out,          // (4)
    int*   __restrict__ cnt,          // 8 counters, stride 16 ints
    float* __restrict__ hbuf,         // 2*2048
    float* __restrict__ feat,         // 8192
    float* __restrict__ hid)          // 2048
{
    const int w    = blockIdx.x;
    const int tid  = threadIdx.x;
    const int v    = tid >> 6;   // wave id == gate type (i,f,g,o)
    const int lane = tid & 63;
    const int r    = lane >> 3;  // row within gate block (h index = 8w+r)
    const int g    = lane & 7;   // 256-col chunk

    __shared__ float4 h_lds4[8 * 65];   // padded: chunk c at float4 index c*65
    __shared__ float  gates_lds[128];
    __shared__ float  c_lds[8];
    __shared__ float  red_lds[4];
    __shared__ float  feat_lds[4 * HDIM]; // 32KB, MLP phase

    const int row = v * HDIM + 8 * w + r;  // global gate row in [0,8192)

    // ---- load this lane's 256 W_hh weights into registers ----
    float4 wreg[64];
    {
        const float4* wp = (const float4*)(W_hh + (size_t)row * HDIM) + g * 64;
#pragma unroll
        for (int i = 0; i < 64; ++i) wreg[i] = wp[i];
    }
    const float brow = b_ih[row] + b_hh[row];
    const float wih0 = W_ih[row * 3 + 0];
    const float wih1 = W_ih[row * 3 + 1];
    const float wih2 = W_ih[row * 3 + 2];
    if (tid < 8) c_lds[tid] = 0.0f;

    // ---- sequential recurrence + action step (t == T_SEQ) ----
    for (int t = 0; t <= T_SEQ; ++t) {
        // phase 0: wait until step t-1 fully published (all 8 counters >= 32*t)
        if (v == 0 && lane < 8) {
            const int target = 32 * t;
            while (__hip_atomic_load(&cnt[lane * 16], __ATOMIC_RELAXED,
                                     __HIP_MEMORY_SCOPE_AGENT) < target)
                __builtin_amdgcn_s_sleep(1);
        }
        __syncthreads();

        // phase 1: stage h_{t-1} into padded LDS (agent-scope loads: L1/L2 bypass)
        {
            const float* hsrc = hbuf + (((t ^ 1) & 1) ? HDIM : 0);
            const int j   = tid * 8;
            const int c   = j >> 8;
            const int off = j & 255;
            float* dst = (float*)&h_lds4[c * 65] + off;
#pragma unroll
            for (int k = 0; k < 8; ++k)
                dst[k] = __hip_atomic_load(hsrc + j + k, __ATOMIC_RELAXED,
                                           __HIP_MEMORY_SCOPE_AGENT);
        }
        __syncthreads();

        // phase 2: partial GEMV from register weights
        float acc = 0.0f;
        {
            const float4* hb = &h_lds4[g * 65];
#pragma unroll
            for (int i = 0; i < 64; ++i) {
                float4 hv = hb[i];
                float4 wv = wreg[i];
                acc += wv.x * hv.x; acc += wv.y * hv.y;
                acc += wv.z * hv.z; acc += wv.w * hv.w;
            }
        }
        // reduce over the 8 col-chunks (lane bits 0..2)
        acc += __shfl_xor(acc, 1, 64);
        acc += __shfl_xor(acc, 2, 64);
        acc += __shfl_xor(acc, 4, 64);

        if (t < T_SEQ) {
            if (g == 0) {
                float xg = wih0 * x[3 * t] + wih1 * x[3 * t + 1] + wih2 * x[3 * t + 2];
                gates_lds[v * 8 + r] = acc + brow + xg;
            }
            __syncthreads();
            if (v == 0) {
                if (lane < 8) {
                    float ig = gates_lds[lane],      fg = gates_lds[8 + lane];
                    float gg = gates_lds[16 + lane], og = gates_lds[24 + lane];
                    float c0 = c_lds[lane];
                    float cn = sigm(fg) * c0 + sigm(ig) * tanhf(gg);
                    float hn = sigm(og) * tanhf(cn);
                    c_lds[lane] = cn;
                    __hip_atomic_store(&hbuf[(t & 1) * HDIM + 8 * w + lane], hn,
                                       __ATOMIC_RELAXED, __HIP_MEMORY_SCOPE_AGENT);
                }
                __threadfence();
                if (lane == 0)
                    __hip_atomic_fetch_add(&cnt[(w & 7) * 16], 1, __ATOMIC_RELAXED,
                                           __HIP_MEMORY_SCOPE_AGENT);
            }
        } else {
            // 4 batched action rollouts from (h_n, c_n); W_hh@h_n already in acc
            const float ld0 = *ldist, lh0 = *lhead;
            if (g == 0) {
#pragma unroll
                for (int a = 0; a < 4; ++a) {
                    float xg = wih0 * ld0 + wih1 * lh0 + wih2 * (float)a;
                    gates_lds[a * 32 + v * 8 + r] = acc + brow + xg;
                }
            }
            __syncthreads();
            if (v == 0) {
                if (lane < 8) {
                    float c0 = c_lds[lane];
#pragma unroll
                    for (int a = 0; a < 4; ++a) {
                        float ig = gates_lds[a * 32 + lane];
                        float fg = gates_lds[a * 32 + 8 + lane];
                        float gg = gates_lds[a * 32 + 16 + lane];
                        float og = gates_lds[a * 32 + 24 + lane];
                        float cn = sigm(fg) * c0 + sigm(ig) * tanhf(gg);
                        float hn = sigm(og) * tanhf(cn);
                        __hip_atomic_store(&feat[a * HDIM + 8 * w + lane], hn,
                                           __ATOMIC_RELAXED, __HIP_MEMORY_SCOPE_AGENT);
                    }
                }
                __threadfence();
                if (lane == 0)
                    __hip_atomic_fetch_add(&cnt[(w & 7) * 16], 1, __ATOMIC_RELAXED,
                                           __HIP_MEMORY_SCOPE_AGENT);
            }
        }
    }

    // ---- MLP layer 1: hid = relu(W1 @ feat + b1), 8 rows per WG ----
    if (v == 0 && lane < 8) {
        const int target = 32 * (T_SEQ + 1);
        while (__hip_atomic_load(&cnt[lane * 16], __ATOMIC_RELAXED,
                                 __HIP_MEMORY_SCOPE_AGENT) < target)
            __builtin_amdgcn_s_sleep(1);
    }
    __syncthreads();
    for (int k = 0; k < 32; ++k) {
        int j = tid + k * 256;
        feat_lds[j] = __hip_atomic_load(feat + j, __ATOMIC_RELAXED,
                                        __HIP_MEMORY_SCOPE_AGENT);
    }
    __syncthreads();
    const float4* flds4 = (const float4*)feat_lds;
    for (int rr = 0; rr < 8; ++rr) {
        const int hrow = 8 * w + rr;
        const float4* Wrow4 = (const float4*)(W1 + (size_t)hrow * 4 * HDIM);
        float p = 0.0f;
#pragma unroll
        for (int s = 0; s < 8; ++s) {
            int idx = s * 256 + tid;
            float4 wv = Wrow4[idx];
            float4 fv = flds4[idx];
            p += wv.x * fv.x + wv.y * fv.y + wv.z * fv.z + wv.w * fv.w;
        }
#pragma unroll
        for (int m = 1; m < 64; m <<= 1) p += __shfl_xor(p, m, 64);
        if (lane == 0) red_lds[v] = p;
        __syncthreads();
        if (tid == 0) {
            float s = red_lds[0] + red_lds[1] + red_lds[2] + red_lds[3] + b1[hrow];
            __hip_atomic_store(&hid[hrow], fmaxf(s, 0.0f), __ATOMIC_RELAXED,
                               __HIP_MEMORY_SCOPE_AGENT);
        }
        __syncthreads();
    }
    __threadfence();
    if (tid == 0)
        __hip_atomic_fetch_add(&cnt[(w & 7) * 16], 1, __ATOMIC_RELAXED,
                               __HIP_MEMORY_SCOPE_AGENT);

    // ---- output layer: WG 0 only ----
    if (w == 0) {
        if (v == 0 && lane < 8) {
            const int target = 32 * (T_SEQ + 2);
            while (__hip_atomic_load(&cnt[lane * 16], __ATOMIC_RELAXED,
                                     __HIP_MEMORY_SCOPE_AGENT) < target)
                __builtin_amdgcn_s_sleep(1);
        }
        __syncthreads();
        float hv8[8];
#pragma unroll
        for (int k = 0; k < 8; ++k)
            hv8[k] = __hip_atomic_load(hid + tid * 8 + k, __ATOMIC_RELAXED,
                                       __HIP_MEMORY_SCOPE_AGENT);
        float po[4];
#pragma unroll
        for (int o = 0; o < 4; ++o) {
            po[o] = 0.0f;
#pragma unroll
            for (int k = 0; k < 8; ++k)
                po[o] += W2[o * HDIM + tid * 8 + k] * hv8[k];
        }
#pragma unroll
        for (int o = 0; o < 4; ++o) {
            float p = po[o];
#pragma unroll
            for (int m = 1; m < 64; m <<= 1) p += __shfl_xor(p, m, 64);
            if (lane == 0) red_lds[v] = p;
            __syncthreads();
            if (tid == 0) out[o] = red_lds[0] + red_lds[1] + red_lds[2] + red_lds[3] + b2[o];
            __syncthreads();
        }
    }
}

extern "C" void kernel_launch(void* const* d_in, const int* in_sizes, int n_in,
                              void* d_out, int out_size, void* d_ws, size_t ws_size,
                              hipStream_t stream) {
    const float* x     = (const float*)d_in[0];
    const float* ldist = (const float*)d_in[1];
    const float* lhead = (const float*)d_in[2];
    const float* W_ih  = (const float*)d_in[3];
    const float* W_hh  = (const float*)d_in[4];
    const float* b_ih  = (const float*)d_in[5];
    const float* b_hh  = (const float*)d_in[6];
    const float* W1    = (const float*)d_in[7];
    const float* b1    = (const float*)d_in[8];
    const float* W2    = (const float*)d_in[9];
    const float* b2    = (const float*)d_in[10];
    float* out = (float*)d_out;

    uint8_t* wsb = (uint8_t*)d_ws;
    int*   cnt  = (int*)wsb;
    float* hbuf = (float*)(wsb + 512);
    float* feat = (float*)(wsb + 512 + 2 * HDIM * 4);
    float* hid  = (float*)(wsb + 512 + 2 * HDIM * 4 + 4 * HDIM * 4);

    // zero counters / hbuf / feat / hid (ws is poisoned 0xAA before every launch)
    hipLaunchKernelGGL(init_ws_kernel, dim3(64), dim3(256), 0, stream, (uint32_t*)d_ws);

    void* args[] = {
        (void*)&x, (void*)&ldist, (void*)&lhead, (void*)&W_ih, (void*)&W_hh,
        (void*)&b_ih, (void*)&b_hh, (void*)&W1, (void*)&b1, (void*)&W2, (void*)&b2,
        (void*)&out, (void*)&cnt, (void*)&hbuf, (void*)&feat, (void*)&hid
    };
    hipError_t e = hipLaunchCooperativeKernel((void*)policy_persistent,
                                              dim3(NB), dim3(NT), args, 0, stream);
    if (e != hipSuccess) {
        // fallback: normal launch — with 1 WG/CU (VGPR-limited) and grid == CU
        // count, all 256 WGs are co-resident anyway.
        hipLaunchKernelGGL(policy_persistent, dim3(NB), dim3(NT), 0, stream,
                           x, ldist, lhead, W_ih, W_hh, b_ih, b_hh, W1, b1, W2, b2,
                           out, cnt, hbuf, feat, hid);
    }
}

// Round 2
// 77280.298 us; speedup vs baseline: 1.2142x; 1.2142x over previous
//
#include <hip/hip_runtime.h>
#include <stdint.h>
#include <stddef.h>

#define T_SEQ 8192
#define HDIM  2048
#define NB    256
#define NT    512

// workspace layout (bytes):
//   [0,512)        : 8 counters, one per 64B line (int at k*16)
//   [512,16896)    : hbuf float[2][2048]
//   [16896,49664)  : feat float[8192]
//   [49664,57856)  : hid  float[2048]
#define WS_ZERO_DWORDS 16384   // zero first 64KB

__global__ void init_ws_kernel(uint32_t* ws) {
    int i = blockIdx.x * blockDim.x + threadIdx.x;
    if (i < WS_ZERO_DWORDS) ws[i] = 0u;
}

__device__ __forceinline__ float sigm(float xv) { return 1.0f / (1.0f + expf(-xv)); }

typedef unsigned long long u64;

__global__ __launch_bounds__(NT, 2) void policy_persistent(
    const float* __restrict__ x,      // (8192,3)
    const float* __restrict__ ldist,  // scalar
    const float* __restrict__ lhead,  // scalar
    const float* __restrict__ W_ih,   // (8192,3)
    const float* __restrict__ W_hh,   // (8192,2048)
    const float* __restrict__ b_ih,   // (8192)
    const float* __restrict__ b_hh,   // (8192)
    const float* __restrict__ W1,     // (2048,8192)
    const float* __restrict__ b1,     // (2048)
    const float* __restrict__ W2,     // (4,2048)
    const float* __restrict__ b2,     // (4)
    float* __restrict__ out,          // (4)
    int*   __restrict__ cnt,          // 8 counters, stride 16 ints
    float* __restrict__ hbuf,         // 2*2048
    float* __restrict__ feat,         // 8192
    float* __restrict__ hid)          // 2048
{
    const int w    = blockIdx.x;
    const int tid  = threadIdx.x;
    const int v    = tid >> 6;         // wave 0..7
    const int lane = tid & 63;
    const int r    = v * 4 + (lane >> 4);  // row within WG block, 0..31
    const int g    = lane & 15;            // 128-col chunk, 0..15
    const int q    = r >> 3;               // gate (i,f,g,o)
    const int p    = r & 7;                // h offset within this WG's 8

    __shared__ float4 h_lds4[16 * 33];   // chunk c at float4 index c*33 (pad 1)
    __shared__ float  gates_lds[128];
    __shared__ float  c_lds[8];
    __shared__ float  red_lds[8];
    __shared__ float  feat_lds[4 * HDIM]; // 32KB, MLP phase

    const int row = q * HDIM + 8 * w + p;  // global gate row in [0,8192)

    // ---- load this lane's 128 W_hh weights into registers (32 float4) ----
    float4 wreg[32];
    {
        const float4* wp = (const float4*)(W_hh + (size_t)row * HDIM) + g * 32;
#pragma unroll
        for (int i = 0; i < 32; ++i) wreg[i] = wp[i];
    }
    const float brow = b_ih[row] + b_hh[row];
    const float wih0 = W_ih[row * 3 + 0];
    const float wih1 = W_ih[row * 3 + 1];
    const float wih2 = W_ih[row * 3 + 2];
    if (tid < 8) c_lds[tid] = 0.0f;

    // ---- sequential recurrence + action step (t == T_SEQ) ----
    for (int t = 0; t <= T_SEQ; ++t) {
        // prefetch x[t] BEFORE the spin — independent of h, hides latency
        float xt0 = 0.f, xt1 = 0.f, xt2 = 0.f;
        if (t < T_SEQ) { xt0 = x[3 * t]; xt1 = x[3 * t + 1]; xt2 = x[3 * t + 2]; }

        // phase 0: wait until step t-1 fully published (all 8 counters >= 32*t)
        if (v == 0 && lane < 8) {
            const int target = 32 * t;
            while (__hip_atomic_load(&cnt[lane * 16], __ATOMIC_RELAXED,
                                     __HIP_MEMORY_SCOPE_AGENT) < target)
                __builtin_amdgcn_s_sleep(1);
        }
        __syncthreads();

        // phase 1: stage h_{t-1} into padded LDS, one float4 per thread
        {
            const float* hsrc = hbuf + (((t ^ 1) & 1) ? HDIM : 0);
            const u64* h64 = (const u64*)hsrc;
            u64 a0 = __hip_atomic_load(h64 + 2 * tid,     __ATOMIC_RELAXED,
                                       __HIP_MEMORY_SCOPE_AGENT);
            u64 a1 = __hip_atomic_load(h64 + 2 * tid + 1, __ATOMIC_RELAXED,
                                       __HIP_MEMORY_SCOPE_AGENT);
            float2 f0 = *(float2*)&a0;
            float2 f1 = *(float2*)&a1;
            h_lds4[(tid >> 5) * 33 + (tid & 31)] = make_float4(f0.x, f0.y, f1.x, f1.y);
        }
        __syncthreads();

        // phase 2: partial GEMV from register weights
        float acc = 0.0f;
        {
            const float4* hb = &h_lds4[g * 33];
#pragma unroll
            for (int i = 0; i < 32; ++i) {
                float4 hv = hb[i];
                float4 wv = wreg[i];
                acc = fmaf(wv.x, hv.x, acc); acc = fmaf(wv.y, hv.y, acc);
                acc = fmaf(wv.z, hv.z, acc); acc = fmaf(wv.w, hv.w, acc);
            }
        }
        // reduce over the 16 col-chunks (lane bits 0..3)
        acc += __shfl_xor(acc, 1, 64);
        acc += __shfl_xor(acc, 2, 64);
        acc += __shfl_xor(acc, 4, 64);
        acc += __shfl_xor(acc, 8, 64);

        if (t < T_SEQ) {
            if (g == 0) {
                float xg = wih0 * xt0 + wih1 * xt1 + wih2 * xt2;
                gates_lds[q * 8 + p] = acc + brow + xg;
            }
            __syncthreads();
            if (v == 0) {
                if (lane < 8) {
                    float ig = gates_lds[lane],      fg = gates_lds[8 + lane];
                    float gg = gates_lds[16 + lane], og = gates_lds[24 + lane];
                    float c0 = c_lds[lane];
                    float cn = sigm(fg) * c0 + sigm(ig) * tanhf(gg);
                    float hn = sigm(og) * tanhf(cn);
                    c_lds[lane] = cn;
                    __hip_atomic_store(&hbuf[(t & 1) * HDIM + 8 * w + lane], hn,
                                       __ATOMIC_RELAXED, __HIP_MEMORY_SCOPE_AGENT);
                }
                __threadfence();
                if (lane == 0)
                    __hip_atomic_fetch_add(&cnt[(w & 7) * 16], 1, __ATOMIC_RELAXED,
                                           __HIP_MEMORY_SCOPE_AGENT);
            }
        } else {
            // 4 batched action rollouts from (h_n, c_n); W_hh@h_n already in acc
            const float ld0 = *ldist, lh0 = *lhead;
            if (g == 0) {
#pragma unroll
                for (int a = 0; a < 4; ++a) {
                    float xg = wih0 * ld0 + wih1 * lh0 + wih2 * (float)a;
                    gates_lds[a * 32 + q * 8 + p] = acc + brow + xg;
                }
            }
            __syncthreads();
            if (v == 0) {
                if (lane < 8) {
                    float c0 = c_lds[lane];
#pragma unroll
                    for (int a = 0; a < 4; ++a) {
                        float ig = gates_lds[a * 32 + lane];
                        float fg = gates_lds[a * 32 + 8 + lane];
                        float gg = gates_lds[a * 32 + 16 + lane];
                        float og = gates_lds[a * 32 + 24 + lane];
                        float cn = sigm(fg) * c0 + sigm(ig) * tanhf(gg);
                        float hn = sigm(og) * tanhf(cn);
                        __hip_atomic_store(&feat[a * HDIM + 8 * w + lane], hn,
                                           __ATOMIC_RELAXED, __HIP_MEMORY_SCOPE_AGENT);
                    }
                }
                __threadfence();
                if (lane == 0)
                    __hip_atomic_fetch_add(&cnt[(w & 7) * 16], 1, __ATOMIC_RELAXED,
                                           __HIP_MEMORY_SCOPE_AGENT);
            }
        }
    }

    // ---- MLP layer 1: hid = relu(W1 @ feat + b1), 8 rows per WG ----
    if (v == 0 && lane < 8) {
        const int target = 32 * (T_SEQ + 1);
        while (__hip_atomic_load(&cnt[lane * 16], __ATOMIC_RELAXED,
                                 __HIP_MEMORY_SCOPE_AGENT) < target)
            __builtin_amdgcn_s_sleep(1);
    }
    __syncthreads();
    {
        const u64* f64 = (const u64*)feat;
        u64* fl64 = (u64*)feat_lds;
#pragma unroll
        for (int k = 0; k < 8; ++k) {
            u64 a = __hip_atomic_load(f64 + k * NT + tid, __ATOMIC_RELAXED,
                                      __HIP_MEMORY_SCOPE_AGENT);
            fl64[k * NT + tid] = a;
        }
    }
    __syncthreads();
    const float4* flds4 = (const float4*)feat_lds;
    for (int rr = 0; rr < 8; ++rr) {
        const int hrow = 8 * w + rr;
        const float4* Wrow4 = (const float4*)(W1 + (size_t)hrow * 4 * HDIM);
        float pacc = 0.0f;
#pragma unroll
        for (int s = 0; s < 4; ++s) {
            int idx = s * NT + tid;
            float4 wv = Wrow4[idx];
            float4 fv = flds4[idx];
            pacc = fmaf(wv.x, fv.x, pacc); pacc = fmaf(wv.y, fv.y, pacc);
            pacc = fmaf(wv.z, fv.z, pacc); pacc = fmaf(wv.w, fv.w, pacc);
        }
#pragma unroll
        for (int m = 1; m < 64; m <<= 1) pacc += __shfl_xor(pacc, m, 64);
        if (lane == 0) red_lds[v] = pacc;
        __syncthreads();
        if (tid == 0) {
            float s = b1[hrow];
#pragma unroll
            for (int k = 0; k < 8; ++k) s += red_lds[k];
            __hip_atomic_store(&hid[hrow], fmaxf(s, 0.0f), __ATOMIC_RELAXED,
                               __HIP_MEMORY_SCOPE_AGENT);
        }
        __syncthreads();
    }
    __threadfence();
    if (tid == 0)
        __hip_atomic_fetch_add(&cnt[(w & 7) * 16], 1, __ATOMIC_RELAXED,
                               __HIP_MEMORY_SCOPE_AGENT);

    // ---- output layer: WG 0 only ----
    if (w == 0) {
        if (v == 0 && lane < 8) {
            const int target = 32 * (T_SEQ + 2);
            while (__hip_atomic_load(&cnt[lane * 16], __ATOMIC_RELAXED,
                                     __HIP_MEMORY_SCOPE_AGENT) < target)
                __builtin_amdgcn_s_sleep(1);
        }
        __syncthreads();
        float hv4[4];
        {
            const u64* h64 = (const u64*)hid;
            u64 a0 = __hip_atomic_load(h64 + 2 * tid,     __ATOMIC_RELAXED,
                                       __HIP_MEMORY_SCOPE_AGENT);
            u64 a1 = __hip_atomic_load(h64 + 2 * tid + 1, __ATOMIC_RELAXED,
                                       __HIP_MEMORY_SCOPE_AGENT);
            float2 f0 = *(float2*)&a0;
            float2 f1 = *(float2*)&a1;
            hv4[0] = f0.x; hv4[1] = f0.y; hv4[2] = f1.x; hv4[3] = f1.y;
        }
#pragma unroll
        for (int o = 0; o < 4; ++o) {
            float pv = 0.0f;
#pragma unroll
            for (int k = 0; k < 4; ++k)
                pv = fmaf(W2[o * HDIM + tid * 4 + k], hv4[k], pv);
#pragma unroll
            for (int m = 1; m < 64; m <<= 1) pv += __shfl_xor(pv, m, 64);
            if (lane == 0) red_lds[v] = pv;
            __syncthreads();
            if (tid == 0) {
                float s = b2[o];
#pragma unroll
                for (int k = 0; k < 8; ++k) s += red_lds[k];
                out[o] = s;
            }
            __syncthreads();
        }
    }
}

extern "C" void kernel_launch(void* const* d_in, const int* in_sizes, int n_in,
                              void* d_out, int out_size, void* d_ws, size_t ws_size,
                              hipStream_t stream) {
    const float* x     = (const float*)d_in[0];
    const float* ldist = (const float*)d_in[1];
    const float* lhead = (const float*)d_in[2];
    const float* W_ih  = (const float*)d_in[3];
    const float* W_hh  = (const float*)d_in[4];
    const float* b_ih  = (const float*)d_in[5];
    const float* b_hh  = (const float*)d_in[6];
    const float* W1    = (const float*)d_in[7];
    const float* b1    = (const float*)d_in[8];
    const float* W2    = (const float*)d_in[9];
    const float* b2    = (const float*)d_in[10];
    float* out = (float*)d_out;

    uint8_t* wsb = (uint8_t*)d_ws;
    int*   cnt  = (int*)wsb;
    float* hbuf = (float*)(wsb + 512);
    float* feat = (float*)(wsb + 512 + 2 * HDIM * 4);
    float* hid  = (float*)(wsb + 512 + 2 * HDIM * 4 + 4 * HDIM * 4);

    // zero counters / hbuf / feat / hid (ws is poisoned 0xAA before every launch)
    hipLaunchKernelGGL(init_ws_kernel, dim3(64), dim3(256), 0, stream, (uint32_t*)d_ws);

    void* args[] = {
        (void*)&x, (void*)&ldist, (void*)&lhead, (void*)&W_ih, (void*)&W_hh,
        (void*)&b_ih, (void*)&b_hh, (void*)&W1, (void*)&b1, (void*)&W2, (void*)&b2,
        (void*)&out, (void*)&cnt, (void*)&hbuf, (void*)&feat, (void*)&hid
    };
    hipError_t e = hipLaunchCooperativeKernel((void*)policy_persistent,
                                              dim3(NB), dim3(NT), args, 0, stream);
    if (e != hipSuccess) {
        // fallback: normal launch — 256 WGs × 512 threads at 1 WG/CU are
        // co-resident on the 256-CU device anyway.
        hipLaunchKernelGGL(policy_persistent, dim3(NB), dim3(NT), 0, stream,
                           x, ldist, lhead, W_ih, W_hh, b_ih, b_hh, W1, b1, W2, b2,
                           out, cnt, hbuf, feat, hid);
    }
}

// Round 3
// 75808.698 us; speedup vs baseline: 1.2377x; 1.0194x over previous
//
#include <hip/hip_runtime.h>
#include <stdint.h>
#include <stddef.h>

#define T_SEQ 8192
#define HDIM  2048
#define NB    256
#define NT    512

// workspace layout (bytes):
//   [0,512)        : 8 counters, one per 64B line (int at k*16)
//   [512,16896)    : hbuf float[2][2048]
//   [16896,49664)  : feat float[8192]
//   [49664,57856)  : hid  float[2048]
#define WS_ZERO_DWORDS 16384   // zero first 64KB

__global__ void init_ws_kernel(uint32_t* ws) {
    int i = blockIdx.x * blockDim.x + threadIdx.x;
    if (i < WS_ZERO_DWORDS) ws[i] = 0u;
}

__device__ __forceinline__ float sigm(float xv) { return 1.0f / (1.0f + expf(-xv)); }

typedef unsigned long long u64;

__global__ __launch_bounds__(NT, 2) void policy_persistent(
    const float* __restrict__ x,      // (8192,3)
    const float* __restrict__ ldist,  // scalar
    const float* __restrict__ lhead,  // scalar
    const float* __restrict__ W_ih,   // (8192,3)
    const float* __restrict__ W_hh,   // (8192,2048)
    const float* __restrict__ b_ih,   // (8192)
    const float* __restrict__ b_hh,   // (8192)
    const float* __restrict__ W1,     // (2048,8192)
    const float* __restrict__ b1,     // (2048)
    const float* __restrict__ W2,     // (4,2048)
    const float* __restrict__ b2,     // (4)
    float* __restrict__ out,          // (4)
    int*   __restrict__ cnt,          // 8 counters, stride 16 ints
    float* __restrict__ hbuf,         // 2*2048
    float* __restrict__ feat,         // 8192
    float* __restrict__ hid)          // 2048
{
    const int w    = blockIdx.x;
    const int tid  = threadIdx.x;
    const int v    = tid >> 6;         // wave 0..7
    const int lane = tid & 63;
    const int r    = v * 4 + (lane >> 4);  // row within WG block, 0..31
    const int g    = lane & 15;            // 128-col chunk, 0..15
    const int q    = r >> 3;               // gate (i,f,g,o)
    const int p    = r & 7;                // h offset within this WG's 8

    __shared__ float4 h_lds4[16 * 33];   // chunk c at float4 index c*33 (pad 1)
    __shared__ float  gates_lds[128];
    __shared__ float  c_lds[8];
    __shared__ float  red_lds[8];
    __shared__ float  feat_lds[4 * HDIM]; // 32KB, MLP phase

    const int row = q * HDIM + 8 * w + p;  // global gate row in [0,8192)

    // ---- load this lane's 128 W_hh weights into registers (32 float4) ----
    // The empty inline-asm "pins" each value: asm defs are NOT rematerializable,
    // so LLVM cannot sink the loads back into the t-loop (which in R2 caused a
    // full 64MB W_hh re-read from L2/L3 every step -> 512 GB of cache traffic).
    float4 wreg[32];
    {
        const float4* wp = (const float4*)(W_hh + (size_t)row * HDIM) + g * 32;
#pragma unroll
        for (int i = 0; i < 32; ++i) {
            wreg[i] = wp[i];
            asm volatile("" : "+v"(wreg[i].x), "+v"(wreg[i].y),
                              "+v"(wreg[i].z), "+v"(wreg[i].w));
        }
    }
    const float brow = b_ih[row] + b_hh[row];
    const float wih0 = W_ih[row * 3 + 0];
    const float wih1 = W_ih[row * 3 + 1];
    const float wih2 = W_ih[row * 3 + 2];
    if (tid < 8) c_lds[tid] = 0.0f;

    // ---- sequential recurrence + action step (t == T_SEQ) ----
    for (int t = 0; t <= T_SEQ; ++t) {
        // prefetch x[t] BEFORE the spin — independent of h, hides latency
        float xt0 = 0.f, xt1 = 0.f, xt2 = 0.f;
        if (t < T_SEQ) { xt0 = x[3 * t]; xt1 = x[3 * t + 1]; xt2 = x[3 * t + 2]; }

        // phase 0: wait until step t-1 fully published (all 8 counters >= 32*t)
        if (v == 0 && lane < 8) {
            const int target = 32 * t;
            while (__hip_atomic_load(&cnt[lane * 16], __ATOMIC_RELAXED,
                                     __HIP_MEMORY_SCOPE_AGENT) < target)
                __builtin_amdgcn_s_sleep(1);
        }
        __syncthreads();

        // phase 1: stage h_{t-1} into padded LDS, one float4 per thread
        {
            const float* hsrc = hbuf + (((t ^ 1) & 1) ? HDIM : 0);
            const u64* h64 = (const u64*)hsrc;
            u64 a0 = __hip_atomic_load(h64 + 2 * tid,     __ATOMIC_RELAXED,
                                       __HIP_MEMORY_SCOPE_AGENT);
            u64 a1 = __hip_atomic_load(h64 + 2 * tid + 1, __ATOMIC_RELAXED,
                                       __HIP_MEMORY_SCOPE_AGENT);
            float2 f0 = *(float2*)&a0;
            float2 f1 = *(float2*)&a1;
            h_lds4[(tid >> 5) * 33 + (tid & 31)] = make_float4(f0.x, f0.y, f1.x, f1.y);
        }
        __syncthreads();

        // phase 2: partial GEMV from register weights
        float acc = 0.0f;
        {
            const float4* hb = &h_lds4[g * 33];
#pragma unroll
            for (int i = 0; i < 32; ++i) {
                float4 hv = hb[i];
                float4 wv = wreg[i];
                acc = fmaf(wv.x, hv.x, acc); acc = fmaf(wv.y, hv.y, acc);
                acc = fmaf(wv.z, hv.z, acc); acc = fmaf(wv.w, hv.w, acc);
            }
        }
        // reduce over the 16 col-chunks (lane bits 0..3)
        acc += __shfl_xor(acc, 1, 64);
        acc += __shfl_xor(acc, 2, 64);
        acc += __shfl_xor(acc, 4, 64);
        acc += __shfl_xor(acc, 8, 64);

        if (t < T_SEQ) {
            if (g == 0) {
                float xg = wih0 * xt0 + wih1 * xt1 + wih2 * xt2;
                gates_lds[q * 8 + p] = acc + brow + xg;
            }
            __syncthreads();
            if (v == 0) {
                if (lane < 8) {
                    float ig = gates_lds[lane],      fg = gates_lds[8 + lane];
                    float gg = gates_lds[16 + lane], og = gates_lds[24 + lane];
                    float c0 = c_lds[lane];
                    float cn = sigm(fg) * c0 + sigm(ig) * tanhf(gg);
                    float hn = sigm(og) * tanhf(cn);
                    c_lds[lane] = cn;
                    __hip_atomic_store(&hbuf[(t & 1) * HDIM + 8 * w + lane], hn,
                                       __ATOMIC_RELAXED, __HIP_MEMORY_SCOPE_AGENT);
                }
                __threadfence();
                if (lane == 0)
                    __hip_atomic_fetch_add(&cnt[(w & 7) * 16], 1, __ATOMIC_RELAXED,
                                           __HIP_MEMORY_SCOPE_AGENT);
            }
        } else {
            // 4 batched action rollouts from (h_n, c_n); W_hh@h_n already in acc
            const float ld0 = *ldist, lh0 = *lhead;
            if (g == 0) {
#pragma unroll
                for (int a = 0; a < 4; ++a) {
                    float xg = wih0 * ld0 + wih1 * lh0 + wih2 * (float)a;
                    gates_lds[a * 32 + q * 8 + p] = acc + brow + xg;
                }
            }
            __syncthreads();
            if (v == 0) {
                if (lane < 8) {
                    float c0 = c_lds[lane];
#pragma unroll
                    for (int a = 0; a < 4; ++a) {
                        float ig = gates_lds[a * 32 + lane];
                        float fg = gates_lds[a * 32 + 8 + lane];
                        float gg = gates_lds[a * 32 + 16 + lane];
                        float og = gates_lds[a * 32 + 24 + lane];
                        float cn = sigm(fg) * c0 + sigm(ig) * tanhf(gg);
                        float hn = sigm(og) * tanhf(cn);
                        __hip_atomic_store(&feat[a * HDIM + 8 * w + lane], hn,
                                           __ATOMIC_RELAXED, __HIP_MEMORY_SCOPE_AGENT);
                    }
                }
                __threadfence();
                if (lane == 0)
                    __hip_atomic_fetch_add(&cnt[(w & 7) * 16], 1, __ATOMIC_RELAXED,
                                           __HIP_MEMORY_SCOPE_AGENT);
            }
        }
    }

    // ---- MLP layer 1: hid = relu(W1 @ feat + b1), 8 rows per WG ----
    if (v == 0 && lane < 8) {
        const int target = 32 * (T_SEQ + 1);
        while (__hip_atomic_load(&cnt[lane * 16], __ATOMIC_RELAXED,
                                 __HIP_MEMORY_SCOPE_AGENT) < target)
            __builtin_amdgcn_s_sleep(1);
    }
    __syncthreads();
    {
        const u64* f64 = (const u64*)feat;
        u64* fl64 = (u64*)feat_lds;
#pragma unroll
        for (int k = 0; k < 8; ++k) {
            u64 a = __hip_atomic_load(f64 + k * NT + tid, __ATOMIC_RELAXED,
                                      __HIP_MEMORY_SCOPE_AGENT);
            fl64[k * NT + tid] = a;
        }
    }
    __syncthreads();
    const float4* flds4 = (const float4*)feat_lds;
    for (int rr = 0; rr < 8; ++rr) {
        const int hrow = 8 * w + rr;
        const float4* Wrow4 = (const float4*)(W1 + (size_t)hrow * 4 * HDIM);
        float pacc = 0.0f;
#pragma unroll
        for (int s = 0; s < 4; ++s) {
            int idx = s * NT + tid;
            float4 wv = Wrow4[idx];
            float4 fv = flds4[idx];
            pacc = fmaf(wv.x, fv.x, pacc); pacc = fmaf(wv.y, fv.y, pacc);
            pacc = fmaf(wv.z, fv.z, pacc); pacc = fmaf(wv.w, fv.w, pacc);
        }
#pragma unroll
        for (int m = 1; m < 64; m <<= 1) pacc += __shfl_xor(pacc, m, 64);
        if (lane == 0) red_lds[v] = pacc;
        __syncthreads();
        if (tid == 0) {
            float s = b1[hrow];
#pragma unroll
            for (int k = 0; k < 8; ++k) s += red_lds[k];
            __hip_atomic_store(&hid[hrow], fmaxf(s, 0.0f), __ATOMIC_RELAXED,
                               __HIP_MEMORY_SCOPE_AGENT);
        }
        __syncthreads();
    }
    __threadfence();
    if (tid == 0)
        __hip_atomic_fetch_add(&cnt[(w & 7) * 16], 1, __ATOMIC_RELAXED,
                               __HIP_MEMORY_SCOPE_AGENT);

    // ---- output layer: WG 0 only ----
    if (w == 0) {
        if (v == 0 && lane < 8) {
            const int target = 32 * (T_SEQ + 2);
            while (__hip_atomic_load(&cnt[lane * 16], __ATOMIC_RELAXED,
                                     __HIP_MEMORY_SCOPE_AGENT) < target)
                __builtin_amdgcn_s_sleep(1);
        }
        __syncthreads();
        float hv4[4];
        {
            const u64* h64 = (const u64*)hid;
            u64 a0 = __hip_atomic_load(h64 + 2 * tid,     __ATOMIC_RELAXED,
                                       __HIP_MEMORY_SCOPE_AGENT);
            u64 a1 = __hip_atomic_load(h64 + 2 * tid + 1, __ATOMIC_RELAXED,
                                       __HIP_MEMORY_SCOPE_AGENT);
            float2 f0 = *(float2*)&a0;
            float2 f1 = *(float2*)&a1;
            hv4[0] = f0.x; hv4[1] = f0.y; hv4[2] = f1.x; hv4[3] = f1.y;
        }
#pragma unroll
        for (int o = 0; o < 4; ++o) {
            float pv = 0.0f;
#pragma unroll
            for (int k = 0; k < 4; ++k)
                pv = fmaf(W2[o * HDIM + tid * 4 + k], hv4[k], pv);
#pragma unroll
            for (int m = 1; m < 64; m <<= 1) pv += __shfl_xor(pv, m, 64);
            if (lane == 0) red_lds[v] = pv;
            __syncthreads();
            if (tid == 0) {
                float s = b2[o];
#pragma unroll
                for (int k = 0; k < 8; ++k) s += red_lds[k];
                out[o] = s;
            }
            __syncthreads();
        }
    }
}

extern "C" void kernel_launch(void* const* d_in, const int* in_sizes, int n_in,
                              void* d_out, int out_size, void* d_ws, size_t ws_size,
                              hipStream_t stream) {
    const float* x     = (const float*)d_in[0];
    const float* ldist = (const float*)d_in[1];
    const float* lhead = (const float*)d_in[2];
    const float* W_ih  = (const float*)d_in[3];
    const float* W_hh  = (const float*)d_in[4];
    const float* b_ih  = (const float*)d_in[5];
    const float* b_hh  = (const float*)d_in[6];
    const float* W1    = (const float*)d_in[7];
    const float* b1    = (const float*)d_in[8];
    const float* W2    = (const float*)d_in[9];
    const float* b2    = (const float*)d_in[10];
    float* out = (float*)d_out;

    uint8_t* wsb = (uint8_t*)d_ws;
    int*   cnt  = (int*)wsb;
    float* hbuf = (float*)(wsb + 512);
    float* feat = (float*)(wsb + 512 + 2 * HDIM * 4);
    float* hid  = (float*)(wsb + 512 + 2 * HDIM * 4 + 4 * HDIM * 4);

    // zero counters / hbuf / feat / hid (ws is poisoned 0xAA before every launch)
    hipLaunchKernelGGL(init_ws_kernel, dim3(64), dim3(256), 0, stream, (uint32_t*)d_ws);

    void* args[] = {
        (void*)&x, (void*)&ldist, (void*)&lhead, (void*)&W_ih, (void*)&W_hh,
        (void*)&b_ih, (void*)&b_hh, (void*)&W1, (void*)&b1, (void*)&W2, (void*)&b2,
        (void*)&out, (void*)&cnt, (void*)&hbuf, (void*)&feat, (void*)&hid
    };
    hipError_t e = hipLaunchCooperativeKernel((void*)policy_persistent,
                                              dim3(NB), dim3(NT), args, 0, stream);
    if (e != hipSuccess) {
        // fallback: normal launch — 256 WGs × 512 threads at 1 WG/CU are
        // co-resident on the 256-CU device anyway.
        hipLaunchKernelGGL(policy_persistent, dim3(NB), dim3(NT), 0, stream,
                           x, ldist, lhead, W_ih, W_hh, b_ih, b_hh, W1, b1, W2, b2,
                           out, cnt, hbuf, feat, hid);
    }
}

// Round 4
// 58849.628 us; speedup vs baseline: 1.5944x; 1.2882x over previous
//
#include <hip/hip_runtime.h>
#include <stdint.h>
#include <stddef.h>

#define T_SEQ 8192
#define HDIM  2048
#define NB    256
#define NT    1024

// workspace layout (bytes):
//   [0,4096)       : 256 per-WG flags, one int per 16B
//   [4096,20480)   : hbuf float[2][2048]
//   [20480,53248)  : feat float[8192]
//   [53248,61440)  : hid  float[2048]
#define WS_ZERO_DWORDS 16384   // zero first 64KB (known-safe size)

__global__ void init_ws_kernel(uint32_t* ws) {
    int i = blockIdx.x * blockDim.x + threadIdx.x;
    if (i < WS_ZERO_DWORDS) ws[i] = 0u;
}

__device__ __forceinline__ float sigm(float xv) { return 1.0f / (1.0f + expf(-xv)); }

typedef unsigned long long u64;

// 1024 threads = 16 waves = 4 waves/SIMD at 1 WG/CU -> VGPR budget 128/wave.
// Weight slice per lane is 64 floats = 64 VGPRs; total demand ~100 fits the
// budget the allocator actually honors (R2/R3: 512-thr version demanded ~190
// and the allocator spilled the weights to scratch -> 512 GB L2/L3 restream).
__global__ __launch_bounds__(NT, 4) void policy_persistent(
    const float* __restrict__ x,      // (8192,3)
    const float* __restrict__ ldist,  // scalar
    const float* __restrict__ lhead,  // scalar
    const float* __restrict__ W_ih,   // (8192,3)
    const float* __restrict__ W_hh,   // (8192,2048)
    const float* __restrict__ b_ih,   // (8192)
    const float* __restrict__ b_hh,   // (8192)
    const float* __restrict__ W1,     // (2048,8192)
    const float* __restrict__ b1,     // (2048)
    const float* __restrict__ W2,     // (4,2048)
    const float* __restrict__ b2,     // (4)
    float* __restrict__ out,          // (4)
    int*   __restrict__ flags,        // 256 flags, stride 4 ints (16B)
    float* __restrict__ hbuf,         // 2*2048
    float* __restrict__ feat,         // 8192
    float* __restrict__ hid)          // 2048
{
    const int w    = blockIdx.x;
    const int tid  = threadIdx.x;
    const int v    = tid >> 6;             // wave 0..15
    const int lane = tid & 63;
    const int r    = 2 * v + (lane >> 5);  // row within WG block, 0..31
    const int g    = lane & 31;            // 64-col chunk, 0..31
    const int q    = r >> 3;               // gate (i,f,g,o)
    const int p    = r & 7;                // h offset within this WG's 8

    __shared__ float4 h_lds4[32 * 17];   // chunk c at float4 index c*17 (pad 1)
    __shared__ float  gates_lds[128];
    __shared__ float  c_lds[8];
    __shared__ float  red_lds[16];
    __shared__ float  feat_lds[4 * HDIM]; // 32KB, MLP phase
    // + 40KB dynamic LDS passed at launch: forces 1 WG/CU.

    const int row = q * HDIM + 8 * w + p;  // global gate row in [0,8192)

    // ---- load this lane's 64 W_hh weights into registers (16 float4) ----
    // asm pin prevents rematerialization; demand fits budget so no spill.
    float4 wreg[16];
    {
        const float4* wp = (const float4*)(W_hh + (size_t)row * HDIM + g * 64);
#pragma unroll
        for (int i = 0; i < 16; ++i) {
            wreg[i] = wp[i];
            asm volatile("" : "+v"(wreg[i].x), "+v"(wreg[i].y),
                              "+v"(wreg[i].z), "+v"(wreg[i].w));
        }
    }
    const float brow = b_ih[row] + b_hh[row];
    const float wih0 = W_ih[row * 3 + 0];
    const float wih1 = W_ih[row * 3 + 1];
    const float wih2 = W_ih[row * 3 + 2];
    if (tid < 8) c_lds[tid] = 0.0f;

    float* stage_dst = (float*)h_lds4 + (tid >> 5) * 68 + ((2 * tid) & 63);
    const float4* hb = h_lds4 + g * 17;

    // ---- sequential recurrence + action step (t == T_SEQ) ----
    for (int t = 0; t <= T_SEQ; ++t) {
        // prefetch x[t] before the spin — independent of h
        float xt0 = 0.f, xt1 = 0.f, xt2 = 0.f;
        if (t < T_SEQ) { xt0 = x[3 * t]; xt1 = x[3 * t + 1]; xt2 = x[3 * t + 2]; }

        // phase 0: wait until every WG has published step t-1 (flag[w] >= t).
        // Plain per-WG stores + parallel per-flag spins: no atomic RMW chains.
        if (tid < 256) {
            while (__hip_atomic_load(&flags[tid * 4], __ATOMIC_RELAXED,
                                     __HIP_MEMORY_SCOPE_AGENT) < t)
                __builtin_amdgcn_s_sleep(1);
        }
        __syncthreads();

        // phase 1: stage h_{t-1} into padded LDS (2 floats per thread)
        {
            const u64* h64 = (const u64*)(hbuf + (((t + 1) & 1) ? HDIM : 0));
            u64 a0 = __hip_atomic_load(h64 + tid, __ATOMIC_RELAXED,
                                       __HIP_MEMORY_SCOPE_AGENT);
            float2 f0 = *(float2*)&a0;
            stage_dst[0] = f0.x; stage_dst[1] = f0.y;
        }
        __syncthreads();

        // phase 2: partial GEMV from register weights
        float acc = 0.0f;
#pragma unroll
        for (int i = 0; i < 16; ++i) {
            float4 hv = hb[i];
            float4 wv = wreg[i];
            acc = fmaf(wv.x, hv.x, acc); acc = fmaf(wv.y, hv.y, acc);
            acc = fmaf(wv.z, hv.z, acc); acc = fmaf(wv.w, hv.w, acc);
        }
        // reduce over the 32 col-chunks (lane bits 0..4)
        acc += __shfl_xor(acc, 1, 64);
        acc += __shfl_xor(acc, 2, 64);
        acc += __shfl_xor(acc, 4, 64);
        acc += __shfl_xor(acc, 8, 64);
        acc += __shfl_xor(acc, 16, 64);

        if (t < T_SEQ) {
            if ((lane & 31) == 0) {
                float xg = wih0 * xt0 + wih1 * xt1 + wih2 * xt2;
                gates_lds[q * 8 + p] = acc + brow + xg;
            }
            __syncthreads();
            if (v == 0) {
                if (lane < 8) {
                    float ig = gates_lds[lane],      fg = gates_lds[8 + lane];
                    float gg = gates_lds[16 + lane], og = gates_lds[24 + lane];
                    float c0 = c_lds[lane];
                    float cn = sigm(fg) * c0 + sigm(ig) * tanhf(gg);
                    float hn = sigm(og) * tanhf(cn);
                    c_lds[lane] = cn;
                    __hip_atomic_store(&hbuf[(t & 1) * HDIM + 8 * w + lane], hn,
                                       __ATOMIC_RELAXED, __HIP_MEMORY_SCOPE_AGENT);
                }
                __threadfence();   // whole wave 0: drains the h stores
                if (lane == 0)
                    __hip_atomic_store(&flags[w * 4], t + 1, __ATOMIC_RELAXED,
                                       __HIP_MEMORY_SCOPE_AGENT);
            }
        } else {
            // 4 batched action rollouts from (h_n, c_n); W_hh@h_n already in acc
            const float ld0 = *ldist, lh0 = *lhead;
            if ((lane & 31) == 0) {
#pragma unroll
                for (int a = 0; a < 4; ++a) {
                    float xg = wih0 * ld0 + wih1 * lh0 + wih2 * (float)a;
                    gates_lds[a * 32 + q * 8 + p] = acc + brow + xg;
                }
            }
            __syncthreads();
            if (v == 0) {
                if (lane < 8) {
                    float c0 = c_lds[lane];
#pragma unroll
                    for (int a = 0; a < 4; ++a) {
                        float ig = gates_lds[a * 32 + lane];
                        float fg = gates_lds[a * 32 + 8 + lane];
                        float gg = gates_lds[a * 32 + 16 + lane];
                        float og = gates_lds[a * 32 + 24 + lane];
                        float cn = sigm(fg) * c0 + sigm(ig) * tanhf(gg);
                        float hn = sigm(og) * tanhf(cn);
                        __hip_atomic_store(&feat[a * HDIM + 8 * w + lane], hn,
                                           __ATOMIC_RELAXED, __HIP_MEMORY_SCOPE_AGENT);
                    }
                }
                __threadfence();
                if (lane == 0)
                    __hip_atomic_store(&flags[w * 4], T_SEQ + 1, __ATOMIC_RELAXED,
                                       __HIP_MEMORY_SCOPE_AGENT);
            }
        }
    }

    // ---- MLP layer 1: hid = relu(W1 @ feat + b1), 8 rows per WG ----
    if (tid < 256) {
        while (__hip_atomic_load(&flags[tid * 4], __ATOMIC_RELAXED,
                                 __HIP_MEMORY_SCOPE_AGENT) < T_SEQ + 1)
            __builtin_amdgcn_s_sleep(1);
    }
    __syncthreads();
    {
        const u64* f64 = (const u64*)feat;
        u64* fl = (u64*)feat_lds;
#pragma unroll
        for (int k = 0; k < 4; ++k)
            fl[k * 1024 + tid] = __hip_atomic_load(f64 + k * 1024 + tid,
                                                   __ATOMIC_RELAXED,
                                                   __HIP_MEMORY_SCOPE_AGENT);
    }
    __syncthreads();
    const float4* flds4 = (const float4*)feat_lds;
    for (int rr = 0; rr < 8; ++rr) {
        const int hrow = 8 * w + rr;
        const float4* Wr = (const float4*)(W1 + (size_t)hrow * 4 * HDIM);
        float pacc = 0.0f;
#pragma unroll
        for (int s = 0; s < 2; ++s) {
            int idx = s * 1024 + tid;
            float4 wv = Wr[idx];
            float4 fv = flds4[idx];
            pacc = fmaf(wv.x, fv.x, pacc); pacc = fmaf(wv.y, fv.y, pacc);
            pacc = fmaf(wv.z, fv.z, pacc); pacc = fmaf(wv.w, fv.w, pacc);
        }
#pragma unroll
        for (int m = 1; m < 64; m <<= 1) pacc += __shfl_xor(pacc, m, 64);
        if (lane == 0) red_lds[v] = pacc;
        __syncthreads();
        if (tid == 0) {
            float s = b1[hrow];
#pragma unroll
            for (int k = 0; k < 16; ++k) s += red_lds[k];
            __hip_atomic_store(&hid[hrow], fmaxf(s, 0.0f), __ATOMIC_RELAXED,
                               __HIP_MEMORY_SCOPE_AGENT);
        }
        __syncthreads();
    }
    __threadfence();
    if (tid == 0)
        __hip_atomic_store(&flags[w * 4], T_SEQ + 2, __ATOMIC_RELAXED,
                           __HIP_MEMORY_SCOPE_AGENT);

    // ---- output layer: WG 0 only ----
    if (w == 0) {
        if (tid < 256) {
            while (__hip_atomic_load(&flags[tid * 4], __ATOMIC_RELAXED,
                                     __HIP_MEMORY_SCOPE_AGENT) < T_SEQ + 2)
                __builtin_amdgcn_s_sleep(1);
        }
        __syncthreads();
        float2 hv;
        {
            u64 a0 = __hip_atomic_load((const u64*)hid + tid, __ATOMIC_RELAXED,
                                       __HIP_MEMORY_SCOPE_AGENT);
            hv = *(float2*)&a0;
        }
#pragma unroll
        for (int o = 0; o < 4; ++o) {
            float pv = W2[o * HDIM + 2 * tid] * hv.x
                     + W2[o * HDIM + 2 * tid + 1] * hv.y;
#pragma unroll
            for (int m = 1; m < 64; m <<= 1) pv += __shfl_xor(pv, m, 64);
            if (lane == 0) red_lds[v] = pv;
            __syncthreads();
            if (tid == 0) {
                float s = b2[o];
#pragma unroll
                for (int k = 0; k < 16; ++k) s += red_lds[k];
                out[o] = s;
            }
            __syncthreads();
        }
    }
}

extern "C" void kernel_launch(void* const* d_in, const int* in_sizes, int n_in,
                              void* d_out, int out_size, void* d_ws, size_t ws_size,
                              hipStream_t stream) {
    const float* x     = (const float*)d_in[0];
    const float* ldist = (const float*)d_in[1];
    const float* lhead = (const float*)d_in[2];
    const float* W_ih  = (const float*)d_in[3];
    const float* W_hh  = (const float*)d_in[4];
    const float* b_ih  = (const float*)d_in[5];
    const float* b_hh  = (const float*)d_in[6];
    const float* W1    = (const float*)d_in[7];
    const float* b1    = (const float*)d_in[8];
    const float* W2    = (const float*)d_in[9];
    const float* b2    = (const float*)d_in[10];
    float* out = (float*)d_out;

    uint8_t* wsb = (uint8_t*)d_ws;
    int*   flags = (int*)wsb;
    float* hbuf  = (float*)(wsb + 4096);
    float* feat  = (float*)(wsb + 20480);
    float* hid   = (float*)(wsb + 53248);

    // zero flags / hbuf / feat / hid (ws is poisoned 0xAA before every launch)
    hipLaunchKernelGGL(init_ws_kernel, dim3(64), dim3(256), 0, stream, (uint32_t*)d_ws);

    void* args[] = {
        (void*)&x, (void*)&ldist, (void*)&lhead, (void*)&W_ih, (void*)&W_hh,
        (void*)&b_ih, (void*)&b_hh, (void*)&W1, (void*)&b1, (void*)&W2, (void*)&b2,
        (void*)&out, (void*)&flags, (void*)&hbuf, (void*)&feat, (void*)&hid
    };
    // 40KB dynamic LDS: static (~42KB) + 40KB > 80KB forces 1 WG/CU.
    hipError_t e = hipLaunchCooperativeKernel((void*)policy_persistent,
                                              dim3(NB), dim3(NT), args,
                                              40960, stream);
    if (e != hipSuccess) {
        hipLaunchKernelGGL(policy_persistent, dim3(NB), dim3(NT), 40960, stream,
                           x, ldist, lhead, W_ih, W_hh, b_ih, b_hh, W1, b1, W2, b2,
                           out, flags, hbuf, feat, hid);
    }
}

// Round 5
// 57367.780 us; speedup vs baseline: 1.6356x; 1.0258x over previous
//
#include <hip/hip_runtime.h>
#include <stdint.h>
#include <stddef.h>

#define T_SEQ 8192
#define HDIM  2048
#define NB    256
#define NT    512

// workspace layout (bytes):
//   [0,4096)       : 256 per-WG flags, one int per 16B
//   [4096,20480)   : hbuf float[2][2048]
//   [20480,53248)  : feat float[8192]
//   [53248,61440)  : hid  float[2048]
#define WS_ZERO_DWORDS 16384   // zero first 64KB

__global__ void init_ws_kernel(uint32_t* ws) {
    int i = blockIdx.x * blockDim.x + threadIdx.x;
    if (i < WS_ZERO_DWORDS) ws[i] = 0u;
}

__device__ __forceinline__ float sigm(float xv) { return 1.0f / (1.0f + expf(-xv)); }

typedef unsigned long long u64;

// amdgpu_waves_per_eu(2,2): pins the backend's occupancy TARGET to 2 waves/EU.
// R2-R4 evidence: with only a min bound, the allocator targets max achievable
// occupancy and spills the weight array to scratch (cost model thinks L2/L3
// scratch reads are cheap) -> 512 GB/run cache restream. With max=2 the VGPR
// pressure target is 256/wave, so the 128 weight VGPRs + ~60 working set fit.
__global__ void __launch_bounds__(NT)
__attribute__((amdgpu_waves_per_eu(2, 2)))
policy_persistent(
    const float* __restrict__ x,      // (8192,3)
    const float* __restrict__ ldist,  // scalar
    const float* __restrict__ lhead,  // scalar
    const float* __restrict__ W_ih,   // (8192,3)
    const float* __restrict__ W_hh,   // (8192,2048)
    const float* __restrict__ b_ih,   // (8192)
    const float* __restrict__ b_hh,   // (8192)
    const float* __restrict__ W1,     // (2048,8192)
    const float* __restrict__ b1,     // (2048)
    const float* __restrict__ W2,     // (4,2048)
    const float* __restrict__ b2,     // (4)
    float* __restrict__ out,          // (4)
    int*   __restrict__ flags,        // 256 flags, stride 4 ints (16B)
    float* __restrict__ hbuf,         // 2*2048
    float* __restrict__ feat,         // 8192
    float* __restrict__ hid)          // 2048
{
    const int w    = blockIdx.x;
    const int tid  = threadIdx.x;
    const int v    = tid >> 6;             // wave 0..7
    const int lane = tid & 63;
    const int r    = v * 4 + (lane >> 4);  // row within WG block, 0..31
    const int g    = lane & 15;            // 128-col chunk, 0..15
    const int q    = r >> 3;               // gate (i,f,g,o)
    const int p    = r & 7;                // h offset within this WG's 8

    __shared__ float4 h_lds4[16 * 33];   // chunk c at float4 index c*33 (pad 1)
    __shared__ float  gates_lds[128];
    __shared__ float  c_lds[8];
    __shared__ float  red_lds[8];
    __shared__ float  feat_lds[4 * HDIM]; // 32KB, MLP phase

    const int row = q * HDIM + 8 * w + p;  // global gate row in [0,8192)

    // ---- load this lane's 128 W_hh weights into registers (32 float4) ----
    // asm pin: prevents rematerialization (R2 lesson).
    float4 wreg[32];
    {
        const float4* wp = (const float4*)(W_hh + (size_t)row * HDIM) + g * 32;
#pragma unroll
        for (int i = 0; i < 32; ++i) {
            wreg[i] = wp[i];
            asm volatile("" : "+v"(wreg[i].x), "+v"(wreg[i].y),
                              "+v"(wreg[i].z), "+v"(wreg[i].w));
        }
    }
    const float brow = b_ih[row] + b_hh[row];
    const float wih0 = W_ih[row * 3 + 0];
    const float wih1 = W_ih[row * 3 + 1];
    const float wih2 = W_ih[row * 3 + 2];
    if (tid < 8) c_lds[tid] = 0.0f;

    // ---- sequential recurrence + action step (t == T_SEQ) ----
    for (int t = 0; t <= T_SEQ; ++t) {
        // prefetch x[t] BEFORE the spin — independent of h, hides latency
        float xt0 = 0.f, xt1 = 0.f, xt2 = 0.f;
        if (t < T_SEQ) { xt0 = x[3 * t]; xt1 = x[3 * t + 1]; xt2 = x[3 * t + 2]; }

        // phase 0: wait until every WG has published step t-1 (flag[w] >= t).
        // Per-WG plain stores + parallel spins: no atomic RMW serialization.
        if (tid < 256) {
            while (__hip_atomic_load(&flags[tid * 4], __ATOMIC_RELAXED,
                                     __HIP_MEMORY_SCOPE_AGENT) < t)
                __builtin_amdgcn_s_sleep(1);
        }
        __syncthreads();

        // phase 1: stage h_{t-1} into padded LDS, one float4 per thread
        {
            const u64* h64 = (const u64*)(hbuf + (((t + 1) & 1) ? HDIM : 0));
            u64 a0 = __hip_atomic_load(h64 + 2 * tid,     __ATOMIC_RELAXED,
                                       __HIP_MEMORY_SCOPE_AGENT);
            u64 a1 = __hip_atomic_load(h64 + 2 * tid + 1, __ATOMIC_RELAXED,
                                       __HIP_MEMORY_SCOPE_AGENT);
            float2 f0 = *(float2*)&a0;
            float2 f1 = *(float2*)&a1;
            h_lds4[(tid >> 5) * 33 + (tid & 31)] = make_float4(f0.x, f0.y, f1.x, f1.y);
        }
        __syncthreads();

        // phase 2: partial GEMV from register weights
        float acc = 0.0f;
        {
            const float4* hb = &h_lds4[g * 33];
#pragma unroll
            for (int i = 0; i < 32; ++i) {
                float4 hv = hb[i];
                float4 wv = wreg[i];
                acc = fmaf(wv.x, hv.x, acc); acc = fmaf(wv.y, hv.y, acc);
                acc = fmaf(wv.z, hv.z, acc); acc = fmaf(wv.w, hv.w, acc);
            }
        }
        // reduce over the 16 col-chunks (lane bits 0..3)
        acc += __shfl_xor(acc, 1, 64);
        acc += __shfl_xor(acc, 2, 64);
        acc += __shfl_xor(acc, 4, 64);
        acc += __shfl_xor(acc, 8, 64);

        if (t < T_SEQ) {
            if (g == 0) {
                float xg = wih0 * xt0 + wih1 * xt1 + wih2 * xt2;
                gates_lds[q * 8 + p] = acc + brow + xg;
            }
            __syncthreads();
            if (v == 0) {
                if (lane < 8) {
                    float ig = gates_lds[lane],      fg = gates_lds[8 + lane];
                    float gg = gates_lds[16 + lane], og = gates_lds[24 + lane];
                    float c0 = c_lds[lane];
                    float cn = sigm(fg) * c0 + sigm(ig) * tanhf(gg);
                    float hn = sigm(og) * tanhf(cn);
                    c_lds[lane] = cn;
                    __hip_atomic_store(&hbuf[(t & 1) * HDIM + 8 * w + lane], hn,
                                       __ATOMIC_RELAXED, __HIP_MEMORY_SCOPE_AGENT);
                }
                __threadfence();   // drain the h stores
                if (lane == 0)
                    __hip_atomic_store(&flags[w * 4], t + 1, __ATOMIC_RELAXED,
                                       __HIP_MEMORY_SCOPE_AGENT);
            }
        } else {
            // 4 batched action rollouts from (h_n, c_n); W_hh@h_n already in acc
            const float ld0 = *ldist, lh0 = *lhead;
            if (g == 0) {
#pragma unroll
                for (int a = 0; a < 4; ++a) {
                    float xg = wih0 * ld0 + wih1 * lh0 + wih2 * (float)a;
                    gates_lds[a * 32 + q * 8 + p] = acc + brow + xg;
                }
            }
            __syncthreads();
            if (v == 0) {
                if (lane < 8) {
                    float c0 = c_lds[lane];
#pragma unroll
                    for (int a = 0; a < 4; ++a) {
                        float ig = gates_lds[a * 32 + lane];
                        float fg = gates_lds[a * 32 + 8 + lane];
                        float gg = gates_lds[a * 32 + 16 + lane];
                        float og = gates_lds[a * 32 + 24 + lane];
                        float cn = sigm(fg) * c0 + sigm(ig) * tanhf(gg);
                        float hn = sigm(og) * tanhf(cn);
                        __hip_atomic_store(&feat[a * HDIM + 8 * w + lane], hn,
                                           __ATOMIC_RELAXED, __HIP_MEMORY_SCOPE_AGENT);
                    }
                }
                __threadfence();
                if (lane == 0)
                    __hip_atomic_store(&flags[w * 4], T_SEQ + 1, __ATOMIC_RELAXED,
                                       __HIP_MEMORY_SCOPE_AGENT);
            }
        }
    }

    // ---- MLP layer 1: hid = relu(W1 @ feat + b1), 8 rows per WG ----
    if (tid < 256) {
        while (__hip_atomic_load(&flags[tid * 4], __ATOMIC_RELAXED,
                                 __HIP_MEMORY_SCOPE_AGENT) < T_SEQ + 1)
            __builtin_amdgcn_s_sleep(1);
    }
    __syncthreads();
    {
        const u64* f64 = (const u64*)feat;
        u64* fl64 = (u64*)feat_lds;
#pragma unroll
        for (int k = 0; k < 8; ++k) {
            u64 a = __hip_atomic_load(f64 + k * NT + tid, __ATOMIC_RELAXED,
                                      __HIP_MEMORY_SCOPE_AGENT);
            fl64[k * NT + tid] = a;
        }
    }
    __syncthreads();
    const float4* flds4 = (const float4*)feat_lds;
    for (int rr = 0; rr < 8; ++rr) {
        const int hrow = 8 * w + rr;
        const float4* Wrow4 = (const float4*)(W1 + (size_t)hrow * 4 * HDIM);
        float pacc = 0.0f;
#pragma unroll
        for (int s = 0; s < 4; ++s) {
            int idx = s * NT + tid;
            float4 wv = Wrow4[idx];
            float4 fv = flds4[idx];
            pacc = fmaf(wv.x, fv.x, pacc); pacc = fmaf(wv.y, fv.y, pacc);
            pacc = fmaf(wv.z, fv.z, pacc); pacc = fmaf(wv.w, fv.w, pacc);
        }
#pragma unroll
        for (int m = 1; m < 64; m <<= 1) pacc += __shfl_xor(pacc, m, 64);
        if (lane == 0) red_lds[v] = pacc;
        __syncthreads();
        if (tid == 0) {
            float s = b1[hrow];
#pragma unroll
            for (int k = 0; k < 8; ++k) s += red_lds[k];
            __hip_atomic_store(&hid[hrow], fmaxf(s, 0.0f), __ATOMIC_RELAXED,
                               __HIP_MEMORY_SCOPE_AGENT);
        }
        __syncthreads();
    }
    __threadfence();
    if (tid == 0)
        __hip_atomic_store(&flags[w * 4], T_SEQ + 2, __ATOMIC_RELAXED,
                           __HIP_MEMORY_SCOPE_AGENT);

    // ---- output layer: WG 0 only ----
    if (w == 0) {
        if (tid < 256) {
            while (__hip_atomic_load(&flags[tid * 4], __ATOMIC_RELAXED,
                                     __HIP_MEMORY_SCOPE_AGENT) < T_SEQ + 2)
                __builtin_amdgcn_s_sleep(1);
        }
        __syncthreads();
        float hv4[4];
        {
            const u64* h64 = (const u64*)hid;
            u64 a0 = __hip_atomic_load(h64 + 2 * tid,     __ATOMIC_RELAXED,
                                       __HIP_MEMORY_SCOPE_AGENT);
            u64 a1 = __hip_atomic_load(h64 + 2 * tid + 1, __ATOMIC_RELAXED,
                                       __HIP_MEMORY_SCOPE_AGENT);
            float2 f0 = *(float2*)&a0;
            float2 f1 = *(float2*)&a1;
            hv4[0] = f0.x; hv4[1] = f0.y; hv4[2] = f1.x; hv4[3] = f1.y;
        }
#pragma unroll
        for (int o = 0; o < 4; ++o) {
            float pv = 0.0f;
#pragma unroll
            for (int k = 0; k < 4; ++k)
                pv = fmaf(W2[o * HDIM + tid * 4 + k], hv4[k], pv);
#pragma unroll
            for (int m = 1; m < 64; m <<= 1) pv += __shfl_xor(pv, m, 64);
            if (lane == 0) red_lds[v] = pv;
            __syncthreads();
            if (tid == 0) {
                float s = b2[o];
#pragma unroll
                for (int k = 0; k < 8; ++k) s += red_lds[k];
                out[o] = s;
            }
            __syncthreads();
        }
    }
}

extern "C" void kernel_launch(void* const* d_in, const int* in_sizes, int n_in,
                              void* d_out, int out_size, void* d_ws, size_t ws_size,
                              hipStream_t stream) {
    const float* x     = (const float*)d_in[0];
    const float* ldist = (const float*)d_in[1];
    const float* lhead = (const float*)d_in[2];
    const float* W_ih  = (const float*)d_in[3];
    const float* W_hh  = (const float*)d_in[4];
    const float* b_ih  = (const float*)d_in[5];
    const float* b_hh  = (const float*)d_in[6];
    const float* W1    = (const float*)d_in[7];
    const float* b1    = (const float*)d_in[8];
    const float* W2    = (const float*)d_in[9];
    const float* b2    = (const float*)d_in[10];
    float* out = (float*)d_out;

    uint8_t* wsb = (uint8_t*)d_ws;
    int*   flags = (int*)wsb;
    float* hbuf  = (float*)(wsb + 4096);
    float* feat  = (float*)(wsb + 20480);
    float* hid   = (float*)(wsb + 53248);

    // zero flags / hbuf / feat / hid (ws is poisoned 0xAA before every launch)
    hipLaunchKernelGGL(init_ws_kernel, dim3(64), dim3(256), 0, stream, (uint32_t*)d_ws);

    void* args[] = {
        (void*)&x, (void*)&ldist, (void*)&lhead, (void*)&W_ih, (void*)&W_hh,
        (void*)&b_ih, (void*)&b_hh, (void*)&W1, (void*)&b1, (void*)&W2, (void*)&b2,
        (void*)&out, (void*)&flags, (void*)&hbuf, (void*)&feat, (void*)&hid
    };
    hipError_t e = hipLaunchCooperativeKernel((void*)policy_persistent,
                                              dim3(NB), dim3(NT), args, 0, stream);
    if (e != hipSuccess) {
        // fallback: normal launch — 8 waves x 256 VGPRs fills the CU register
        // file, so 256 WGs on 256 CUs are co-resident anyway.
        hipLaunchKernelGGL(policy_persistent, dim3(NB), dim3(NT), 0, stream,
                           x, ldist, lhead, W_ih, W_hh, b_ih, b_hh, W1, b1, W2, b2,
                           out, flags, hbuf, feat, hid);
    }
}